// Round 10
// baseline (214.208 us; speedup 1.0000x reference)
//
#include <hip/hip_runtime.h>

#define HIDDEN 1024
#define NB 8
#define SEQ 2048
#define DH 64

typedef long long i64;
typedef unsigned short u16;
typedef __attribute__((ext_vector_type(8))) short short8;   // 8 bf16 (4 VGPRs)
typedef __attribute__((ext_vector_type(4))) float f32x4;

#define MFMA16 __builtin_amdgcn_mfma_f32_16x16x32_bf16

__device__ __forceinline__ u16 f2bf(float x) {
    unsigned u = __float_as_uint(x);
    u = u + 0x7FFFu + ((u >> 16) & 1u);       // RNE
    return (u16)(u >> 16);
}
__device__ __forceinline__ float bf2f(u16 h) {
    return __uint_as_float(((unsigned)h) << 16);
}
__device__ __forceinline__ void gl_lds16(const void* g, void* l) {
    __builtin_amdgcn_global_load_lds(
        (const __attribute__((address_space(1))) unsigned int*)g,
        (__attribute__((address_space(3))) unsigned int*)l, 16, 0, 0);
}

// Dekker truncation split of 8 fp32 -> hi/lo bf16 short8 (residual ~2^-16|x|).
__device__ __forceinline__ void split8(const float4 a, const float4 b,
                                       short8& hi, short8& lo) {
    const float xs[8] = {a.x, a.y, a.z, a.w, b.x, b.y, b.z, b.w};
    #pragma unroll
    for (int j = 0; j < 8; ++j) {
        const unsigned u = __float_as_uint(xs[j]);
        const unsigned hf = u & 0xFFFF0000u;
        hi[j] = (short)(u >> 16);                       // truncate
        const float l = xs[j] - __uint_as_float(hf);    // exact remainder
        lo[j] = (short)(__float_as_uint(l) >> 16);      // truncate
    }
}

// ---------------------------------------------------------------------------
// Prepass: W[1024][64] -> Wt_hi/Wt_lo[64][1024] bf16 (transposed + split).
// (byte-identical to the round-9 passing version)
// ---------------------------------------------------------------------------
__global__ __launch_bounds__(256) void wt_prep(
    const float* __restrict__ Wq, const float* __restrict__ Wk, const float* __restrict__ Wv,
    u16* __restrict__ Wth, u16* __restrict__ Wtl)
{
    const int te = blockIdx.x >> 4, hb = blockIdx.x & 15;
    const float* W = te == 0 ? Wq : te == 1 ? Wk : Wv;
    __shared__ float tile[64][65];
    const int t = threadIdx.x;
    const int hr = t >> 2, c0 = (t & 3) << 4;
    #pragma unroll
    for (int j = 0; j < 16; j += 4) {
        float4 w4 = *(const float4*)(W + (i64)(hb * 64 + hr) * DH + c0 + j);
        tile[hr][c0 + j] = w4.x; tile[hr][c0 + j + 1] = w4.y;
        tile[hr][c0 + j + 2] = w4.z; tile[hr][c0 + j + 3] = w4.w;
    }
    __syncthreads();
    const int n = t >> 2, h0 = (t & 3) << 4;
    const i64 base = (i64)te * DH * HIDDEN + (i64)n * HIDDEN + hb * 64 + h0;
    #pragma unroll
    for (int j = 0; j < 16; ++j) {
        float x = tile[h0 + j][n];
        u16 h = f2bf(x);
        Wth[base + j] = h;
        Wtl[base + j] = f2bf(x - bf2f(h));
    }
}

// ---------------------------------------------------------------------------
// Projection v5: barrier-free, LDS-free register pipeline.
// 1 wave/block, 16 rows x 64 cols per wave, grid (1024, 3).
// A-fragments read directly from row-major fp32 global (v2's proven layout),
// register-double-buffered 2 k-steps ahead; W hi/lo fragments are 16
// clustered contiguous 16B loads/step from L2-resident Wt. Truncation split
// in-register. No syncthreads, no LDS, no inline asm.
// ---------------------------------------------------------------------------
__global__ __launch_bounds__(64) void proj_mfma5(
    const float* __restrict__ qh, const float* __restrict__ kh, const float* __restrict__ vh,
    const u16* __restrict__ Wth, const u16* __restrict__ Wtl,
    const float* __restrict__ bq, const float* __restrict__ bk, const float* __restrict__ bv,
    u16* __restrict__ Qb, u16* __restrict__ Kb, u16* __restrict__ Vt)
{
    const int te = blockIdx.y;
    const float* A    = te == 0 ? qh : te == 1 ? kh : vh;
    const float* bias = te == 0 ? bq : te == 1 ? bk : bv;
    const int row0 = blockIdx.x << 4;
    const int lane = threadIdx.x;
    const int lr = lane & 15, lg = lane >> 4;

    const u16* WH = Wth + (i64)te * DH * HIDDEN;
    const u16* WL = Wtl + (i64)te * DH * HIDDEN;
    const float* arow = A + (i64)(row0 + lr) * HIDDEN + (lg << 3);
    const i64 wbase = (i64)lr * HIDDEN + (lg << 3);

    f32x4 acc[4] = {};

    // A-prefetch slots: 4 float4 per BK=64 step (k offsets +0,+4,+32,+36)
    float4 ap0[4], ap1[4];
#define LDA(dst, kk) { \
        dst[0] = *(const float4*)(arow + (kk));      \
        dst[1] = *(const float4*)(arow + (kk) + 4);  \
        dst[2] = *(const float4*)(arow + (kk) + 32); \
        dst[3] = *(const float4*)(arow + (kk) + 36); }
    LDA(ap0, 0)
    LDA(ap1, 64)

#define PROJ_STEP(kk, ap) { \
        short8 ah0, al0, ah1, al1; \
        split8(ap[0], ap[1], ah0, al0); \
        split8(ap[2], ap[3], ah1, al1); \
        const int kr = ((kk) + 128) & 1023;   /* wrap-clamp: valid, unused data */ \
        LDA(ap, kr) \
        short8 bh[4][2], bl[4][2]; \
        _Pragma("unroll") \
        for (int nt = 0; nt < 4; ++nt) { \
            _Pragma("unroll") \
            for (int s = 0; s < 2; ++s) { \
                const i64 off = (i64)(nt * 16) * HIDDEN + wbase + (kk) + s * 32; \
                bh[nt][s] = *(const short8*)(WH + off); \
                bl[nt][s] = *(const short8*)(WL + off); \
            } \
        } \
        _Pragma("unroll") \
        for (int nt = 0; nt < 4; ++nt) { \
            acc[nt] = MFMA16(ah0, bh[nt][0], acc[nt], 0, 0, 0); \
            acc[nt] = MFMA16(ah0, bl[nt][0], acc[nt], 0, 0, 0); \
            acc[nt] = MFMA16(al0, bh[nt][0], acc[nt], 0, 0, 0); \
            acc[nt] = MFMA16(ah1, bh[nt][1], acc[nt], 0, 0, 0); \
            acc[nt] = MFMA16(ah1, bl[nt][1], acc[nt], 0, 0, 0); \
            acc[nt] = MFMA16(al1, bh[nt][1], acc[nt], 0, 0, 0); \
        } }

    #pragma unroll 1
    for (int k0 = 0; k0 < HIDDEN; k0 += 128) {
        PROJ_STEP(k0, ap0)
        PROJ_STEP(k0 + 64, ap1)
    }

    // epilogue: D layout col=lane&15 (within nt), row=(lane>>4)*4+reg
    #pragma unroll
    for (int nt = 0; nt < 4; ++nt) {
        const int col = nt * 16 + lr;
        const float bb = bias[col];
        #pragma unroll
        for (int r = 0; r < 4; ++r) {
            const i64 grow = row0 + (lg << 2) + r;
            const u16 v = f2bf(acc[nt][r] + bb);
            if (te == 0)      Qb[grow * DH + col] = v;
            else if (te == 1) Kb[grow * DH + col] = v;
            else {
                const i64 bb2 = grow >> 11, key = grow & 2047;
                Vt[(bb2 * DH + col) * SEQ + key] = v;
            }
        }
    }
#undef PROJ_STEP
#undef LDA
}

// ---------------------------------------------------------------------------
// Attention: 1024 single-wave blocks (16 q-rows each), no barriers.
// (byte-identical to the round-9 passing version)
// ---------------------------------------------------------------------------
__global__ __launch_bounds__(64) void attn_mfma(
    const u16* __restrict__ Qb, const u16* __restrict__ Kb, const u16* __restrict__ Vt,
    const int* __restrict__ mask, float* __restrict__ out)
{
    __shared__ __attribute__((aligned(16))) u16 Kl[2][64 * 64];
    __shared__ __attribute__((aligned(16))) u16 Vl[2][64 * 64];
    __shared__ __attribute__((aligned(16))) u16 Pl[16][72];

    const int lane = threadIdx.x;
    const int lr = lane & 15, lg = lane >> 4;
    const int b  = blockIdx.x >> 7;
    const int q0 = (blockIdx.x & 127) << 4;

    const i64 qrow = (i64)b * SEQ + q0 + lr;
    const short8 qf0 = *(const short8*)(Qb + qrow * DH + lg * 8);
    const short8 qf1 = *(const short8*)(Qb + qrow * DH + 32 + lg * 8);

    const int srow = lane >> 3;   // 0..7 (+8i)
    const int scb  = lane & 7;    // 16B block

    f32x4 oacc[4] = {};
    float rs0 = 0.f, rs1 = 0.f, rs2 = 0.f, rs3 = 0.f;

    // prologue: stage tile 0 into buf 0 (16 loads)
    {
        const i64 kbase = (i64)b * SEQ;
        #pragma unroll
        for (int i = 0; i < 8; ++i) {
            int row = i * 8 + srow, cb = scb ^ (row & 7);
            gl_lds16(Kb + (kbase + row) * DH + cb * 8, &Kl[0][i * 512]);
        }
        #pragma unroll
        for (int i = 0; i < 8; ++i) {
            int row = i * 8 + srow, cb = scb ^ (row & 7);
            gl_lds16(Vt + ((i64)b * DH + row) * SEQ + cb * 8, &Vl[0][i * 512]);
        }
    }

    #pragma unroll 1
    for (int t = 0; t < 32; ++t) {
        const int kt = t * 64;
        const int buf = t & 1;

        int mv[16];
        #pragma unroll
        for (int tt = 0; tt < 4; ++tt)
            #pragma unroll
            for (int r = 0; r < 4; ++r)
                mv[tt * 4 + r] =
                    mask[((i64)b * SEQ + q0 + lg * 4 + r) * SEQ + kt + tt * 16 + lr];

        if (t < 31) {
            const int kn = kt + 64;
            const i64 kbase = (i64)b * SEQ + kn;
            #pragma unroll
            for (int i = 0; i < 8; ++i) {
                int row = i * 8 + srow, cb = scb ^ (row & 7);
                gl_lds16(Kb + (kbase + row) * DH + cb * 8, &Kl[buf ^ 1][i * 512]);
            }
            #pragma unroll
            for (int i = 0; i < 8; ++i) {
                int row = i * 8 + srow, cb = scb ^ (row & 7);
                gl_lds16(Vt + ((i64)b * DH + row) * SEQ + kn + cb * 8, &Vl[buf ^ 1][i * 512]);
            }
            asm volatile("s_waitcnt vmcnt(32)" ::: "memory");
        } else {
            asm volatile("s_waitcnt vmcnt(16)" ::: "memory");
        }

        f32x4 sacc[4] = {};
        #pragma unroll
        for (int tt = 0; tt < 4; ++tt) {
            int row = tt * 16 + lr, x = row & 7;
            short8 k0 = *(const short8*)&Kl[buf][row * 64 + ((lg) ^ x) * 8];
            short8 k1 = *(const short8*)&Kl[buf][row * 64 + ((lg + 4) ^ x) * 8];
            sacc[tt] = MFMA16(qf0, k0, sacc[tt], 0, 0, 0);
            sacc[tt] = MFMA16(qf1, k1, sacc[tt], 0, 0, 0);
        }

        #pragma unroll
        for (int tt = 0; tt < 4; ++tt) {
            #pragma unroll
            for (int r = 0; r < 4; ++r) {
                float p = (mv[tt * 4 + r] != 0) ? __expf(sacc[tt][r] * 0.125f) : 0.0f;
                if      (r == 0) rs0 += p;
                else if (r == 1) rs1 += p;
                else if (r == 2) rs2 += p;
                else             rs3 += p;
                Pl[lg * 4 + r][tt * 16 + lr] = f2bf(p);
            }
        }

        const short8 p0 = *(const short8*)&Pl[lr][lg * 8];
        const short8 p1 = *(const short8*)&Pl[lr][32 + lg * 8];
        #pragma unroll
        for (int vt = 0; vt < 4; ++vt) {
            int row = vt * 16 + lr, x = row & 7;
            short8 v0 = *(const short8*)&Vl[buf][row * 64 + ((lg) ^ x) * 8];
            short8 v1 = *(const short8*)&Vl[buf][row * 64 + ((lg + 4) ^ x) * 8];
            oacc[vt] = MFMA16(p0, v0, oacc[vt], 0, 0, 0);
            oacc[vt] = MFMA16(p1, v1, oacc[vt], 0, 0, 0);
        }
    }

    float rs[4] = {rs0, rs1, rs2, rs3};
    #pragma unroll
    for (int r = 0; r < 4; ++r) {
        float v = rs[r];
        v += __shfl_xor(v, 1, 64);
        v += __shfl_xor(v, 2, 64);
        v += __shfl_xor(v, 4, 64);
        v += __shfl_xor(v, 8, 64);
        rs[r] = 1.0f / v;
    }
    #pragma unroll
    for (int vt = 0; vt < 4; ++vt)
        #pragma unroll
        for (int r = 0; r < 4; ++r)
            out[((i64)b * SEQ + q0 + lg * 4 + r) * DH + vt * 16 + lr] = oacc[vt][r] * rs[r];
}

extern "C" void kernel_launch(void* const* d_in, const int* in_sizes, int n_in,
                              void* d_out, int out_size, void* d_ws, size_t ws_size,
                              hipStream_t stream) {
    const float* kh   = (const float*)d_in[0];
    const float* qh   = (const float*)d_in[1];
    const float* vh   = (const float*)d_in[2];
    const int*   mask = (const int*)  d_in[3];
    const float* Wq   = (const float*)d_in[4];
    const float* bq   = (const float*)d_in[5];
    const float* Wk   = (const float*)d_in[6];
    const float* bk   = (const float*)d_in[7];
    const float* Wv   = (const float*)d_in[8];
    const float* bv   = (const float*)d_in[9];
    float* out = (float*)d_out;

    u16* Wth = (u16*)d_ws;                       // 3*64*1024
    u16* Wtl = Wth + 3 * DH * HIDDEN;            // 3*64*1024
    u16* Qb  = Wtl + 3 * DH * HIDDEN;            // 8*2048*64
    u16* Kb  = Qb + (i64)NB * SEQ * DH;
    u16* Vt  = Kb + (i64)NB * SEQ * DH;          // [b][vd][key]

    wt_prep<<<48, 256, 0, stream>>>(Wq, Wk, Wv, Wth, Wtl);
    proj_mfma5<<<dim3(1024, 3), 64, 0, stream>>>(qh, kh, vh, Wth, Wtl,
                                                 bq, bk, bv, Qb, Kb, Vt);
    attn_mfma<<<1024, 64, 0, stream>>>(Qb, Kb, Vt, mask, out);
}

// Round 11
// 144.861 us; speedup vs baseline: 1.4787x; 1.4787x over previous
//
#include <hip/hip_runtime.h>

#define HIDDEN 1024
#define NB 8
#define SEQ 2048
#define DH 64

typedef long long i64;
typedef unsigned short u16;
typedef __attribute__((ext_vector_type(8))) short short8;   // 8 bf16 (4 VGPRs)
typedef __attribute__((ext_vector_type(4))) float f32x4;

#define MFMA16 __builtin_amdgcn_mfma_f32_16x16x32_bf16

__device__ __forceinline__ u16 f2bf(float x) {
    unsigned u = __float_as_uint(x);
    u = u + 0x7FFFu + ((u >> 16) & 1u);       // RNE
    return (u16)(u >> 16);
}
__device__ __forceinline__ float bf2f(u16 h) {
    return __uint_as_float(((unsigned)h) << 16);
}
__device__ __forceinline__ void gl_lds16(const void* g, void* l) {
    __builtin_amdgcn_global_load_lds(
        (const __attribute__((address_space(1))) unsigned int*)g,
        (__attribute__((address_space(3))) unsigned int*)l, 16, 0, 0);
}

// ---------------------------------------------------------------------------
// Prepass: W[1024][64] -> Wt_hi/Wt_lo[64][1024] bf16 (transposed + split).
// (byte-identical to the round-9 passing version)
// ---------------------------------------------------------------------------
__global__ __launch_bounds__(256) void wt_prep(
    const float* __restrict__ Wq, const float* __restrict__ Wk, const float* __restrict__ Wv,
    u16* __restrict__ Wth, u16* __restrict__ Wtl)
{
    const int te = blockIdx.x >> 4, hb = blockIdx.x & 15;
    const float* W = te == 0 ? Wq : te == 1 ? Wk : Wv;
    __shared__ float tile[64][65];
    const int t = threadIdx.x;
    const int hr = t >> 2, c0 = (t & 3) << 4;
    #pragma unroll
    for (int j = 0; j < 16; j += 4) {
        float4 w4 = *(const float4*)(W + (i64)(hb * 64 + hr) * DH + c0 + j);
        tile[hr][c0 + j] = w4.x; tile[hr][c0 + j + 1] = w4.y;
        tile[hr][c0 + j + 2] = w4.z; tile[hr][c0 + j + 3] = w4.w;
    }
    __syncthreads();
    const int n = t >> 2, h0 = (t & 3) << 4;
    const i64 base = (i64)te * DH * HIDDEN + (i64)n * HIDDEN + hb * 64 + h0;
    #pragma unroll
    for (int j = 0; j < 16; ++j) {
        float x = tile[h0 + j][n];
        u16 h = f2bf(x);
        Wth[base + j] = h;
        Wtl[base + j] = f2bf(x - bf2f(h));
    }
}

// ---------------------------------------------------------------------------
// Projection v6: fine-grain waves + 2-phase LDS pipeline.
// Block = 256 thr = 4 waves over a 32-row x 64-col tile; wave w computes the
// 16x32 slice rows (w&1)*16.., cols (w>>1)*32.. (one MFMA tile x 2 nt).
// Grid 512x3 = 1536 blocks -> 6 blocks/CU (LDS-capped) = 24 waves/CU.
// BK=32, 32 steps. Per step: A (32x32 fp32 = 4KB) reg-staged with in-register
// Dekker hi/lo split (1 float4/thread); B (64n x 32k hi+lo = 8KB) staged
// linearly via global_load_lds from L2-resident Wt. T3-lite loop:
// issue stage(t+1) -> compute(t) -> write A(t+1) -> vmcnt(0) + barrier.
// ---------------------------------------------------------------------------
__global__ __launch_bounds__(256) void proj_mfma6(
    const float* __restrict__ qh, const float* __restrict__ kh, const float* __restrict__ vh,
    const u16* __restrict__ Wth, const u16* __restrict__ Wtl,
    const float* __restrict__ bq, const float* __restrict__ bk, const float* __restrict__ bv,
    u16* __restrict__ Qb, u16* __restrict__ Kb, u16* __restrict__ Vt)
{
    const int te = blockIdx.y;
    const float* A    = te == 0 ? qh : te == 1 ? kh : vh;
    const float* bias = te == 0 ? bq : te == 1 ? bk : bv;
    const int row0 = blockIdx.x << 5;          // 512 tiles of 32 rows
    const int t = threadIdx.x;
    const int w = t >> 6, lane = t & 63;
    const int lr = lane & 15, lg = lane >> 4;
    const int wrh = (w & 1) << 4;              // wave row-half: 0 / 16
    const int wch = (w >> 1) << 5;             // wave col-half: 0 / 32

    // A padded to 40 u16/row (80 B: 20-dword stride spreads banks).
    __shared__ __attribute__((aligned(16))) u16 AhL[2][32][40];
    __shared__ __attribute__((aligned(16))) u16 AlL[2][32][40];
    __shared__ __attribute__((aligned(16))) u16 BhL[2][64][32];
    __shared__ __attribute__((aligned(16))) u16 BlL[2][64][32];

    const u16* WH = Wth + (i64)te * DH * HIDDEN;
    const u16* WL = Wtl + (i64)te * DH * HIDDEN;

    // A staging role: thread t loads A[row0 + (t>>3)][k0 + (t&7)*4 ..+3]
    const int ar = t >> 3;                     // 0..31
    const int ak = (t & 7) << 2;               // 0,4,..,28
    const float* Ag = A + (i64)(row0 + ar) * HIDDEN + ak;
    // B staging: slot t -> n = t>>2, 16B-block cb = t&3 (linear, coalesced)
    const int bn = t >> 2, bcb = t & 3;
    const u16* BgH = WH + (i64)bn * HIDDEN + (bcb << 3);
    const u16* BgL = WL + (i64)bn * HIDDEN + (bcb << 3);

    f32x4 acc[2] = {};

#define SPLIT4(x4, h, l) { \
        const float xs_[4] = {x4.x, x4.y, x4.z, x4.w}; \
        _Pragma("unroll") \
        for (int j_ = 0; j_ < 4; ++j_) { \
            const unsigned u_ = __float_as_uint(xs_[j_]); \
            h[j_] = (u16)(u_ >> 16); \
            const float l_ = xs_[j_] - __uint_as_float(u_ & 0xFFFF0000u); \
            l[j_] = (u16)(__float_as_uint(l_) >> 16); \
        } }

    // ---- prologue: stage step 0 into buf 0 ----
    {
        float4 a4 = *(const float4*)(Ag);
        u16 h[4], l[4];
        SPLIT4(a4, h, l)
        ushort4 hp = {h[0], h[1], h[2], h[3]};
        ushort4 lp = {l[0], l[1], l[2], l[3]};
        *(ushort4*)&AhL[0][ar][ak] = hp;
        *(ushort4*)&AlL[0][ar][ak] = lp;
        gl_lds16(BgH, &BhL[0][w << 4][0]);
        gl_lds16(BgL, &BlL[0][w << 4][0]);
        asm volatile("s_waitcnt vmcnt(0)" ::: "memory");
        __syncthreads();
    }

    int buf = 0;
    #pragma unroll 1
    for (int s = 0; s < 32; ++s) {
        const int kn = ((s + 1) & 31) << 5;    // next k-base (wrap: last is unused)

        // issue next-step loads first (latency hides under compute)
        float4 an = *(const float4*)(Ag + kn);
        gl_lds16(BgH + kn, &BhL[buf ^ 1][w << 4][0]);
        gl_lds16(BgL + kn, &BlL[buf ^ 1][w << 4][0]);

        // compute on current buffer
        const short8 ah = *(const short8*)&AhL[buf][wrh + lr][lg << 3];
        const short8 al = *(const short8*)&AlL[buf][wrh + lr][lg << 3];
        #pragma unroll
        for (int nt = 0; nt < 2; ++nt) {
            const int n = wch + nt * 16 + lr;
            const short8 bh = *(const short8*)&BhL[buf][n][lg << 3];
            const short8 bl = *(const short8*)&BlL[buf][n][lg << 3];
            acc[nt] = MFMA16(ah, bh, acc[nt], 0, 0, 0);
            acc[nt] = MFMA16(ah, bl, acc[nt], 0, 0, 0);
            acc[nt] = MFMA16(al, bh, acc[nt], 0, 0, 0);
        }

        // convert + write next A tile into the other buffer
        {
            u16 h[4], l[4];
            SPLIT4(an, h, l)
            ushort4 hp = {h[0], h[1], h[2], h[3]};
            ushort4 lp = {l[0], l[1], l[2], l[3]};
            *(ushort4*)&AhL[buf ^ 1][ar][ak] = hp;
            *(ushort4*)&AlL[buf ^ 1][ar][ak] = lp;
        }

        asm volatile("s_waitcnt vmcnt(0)" ::: "memory");
        __syncthreads();
        buf ^= 1;
    }
#undef SPLIT4

    // epilogue: D layout col=lane&15 (within nt), row=(lane>>4)*4+reg
    #pragma unroll
    for (int nt = 0; nt < 2; ++nt) {
        const int col = wch + nt * 16 + lr;
        const float bb = bias[col];
        #pragma unroll
        for (int r = 0; r < 4; ++r) {
            const i64 grow = row0 + wrh + (lg << 2) + r;
            const u16 v = f2bf(acc[nt][r] + bb);
            if (te == 0)      Qb[grow * DH + col] = v;
            else if (te == 1) Kb[grow * DH + col] = v;
            else {
                const i64 bb2 = grow >> 11, key = grow & 2047;
                Vt[(bb2 * DH + col) * SEQ + key] = v;
            }
        }
    }
}

// ---------------------------------------------------------------------------
// Attention: 1024 single-wave blocks (16 q-rows each), no barriers.
// (byte-identical to the round-9 passing version)
// ---------------------------------------------------------------------------
__global__ __launch_bounds__(64) void attn_mfma(
    const u16* __restrict__ Qb, const u16* __restrict__ Kb, const u16* __restrict__ Vt,
    const int* __restrict__ mask, float* __restrict__ out)
{
    __shared__ __attribute__((aligned(16))) u16 Kl[2][64 * 64];
    __shared__ __attribute__((aligned(16))) u16 Vl[2][64 * 64];
    __shared__ __attribute__((aligned(16))) u16 Pl[16][72];

    const int lane = threadIdx.x;
    const int lr = lane & 15, lg = lane >> 4;
    const int b  = blockIdx.x >> 7;
    const int q0 = (blockIdx.x & 127) << 4;

    const i64 qrow = (i64)b * SEQ + q0 + lr;
    const short8 qf0 = *(const short8*)(Qb + qrow * DH + lg * 8);
    const short8 qf1 = *(const short8*)(Qb + qrow * DH + 32 + lg * 8);

    const int srow = lane >> 3;   // 0..7 (+8i)
    const int scb  = lane & 7;    // 16B block

    f32x4 oacc[4] = {};
    float rs0 = 0.f, rs1 = 0.f, rs2 = 0.f, rs3 = 0.f;

    // prologue: stage tile 0 into buf 0 (16 loads)
    {
        const i64 kbase = (i64)b * SEQ;
        #pragma unroll
        for (int i = 0; i < 8; ++i) {
            int row = i * 8 + srow, cb = scb ^ (row & 7);
            gl_lds16(Kb + (kbase + row) * DH + cb * 8, &Kl[0][i * 512]);
        }
        #pragma unroll
        for (int i = 0; i < 8; ++i) {
            int row = i * 8 + srow, cb = scb ^ (row & 7);
            gl_lds16(Vt + ((i64)b * DH + row) * SEQ + cb * 8, &Vl[0][i * 512]);
        }
    }

    #pragma unroll 1
    for (int t = 0; t < 32; ++t) {
        const int kt = t * 64;
        const int buf = t & 1;

        int mv[16];
        #pragma unroll
        for (int tt = 0; tt < 4; ++tt)
            #pragma unroll
            for (int r = 0; r < 4; ++r)
                mv[tt * 4 + r] =
                    mask[((i64)b * SEQ + q0 + lg * 4 + r) * SEQ + kt + tt * 16 + lr];

        if (t < 31) {
            const int kn = kt + 64;
            const i64 kbase = (i64)b * SEQ + kn;
            #pragma unroll
            for (int i = 0; i < 8; ++i) {
                int row = i * 8 + srow, cb = scb ^ (row & 7);
                gl_lds16(Kb + (kbase + row) * DH + cb * 8, &Kl[buf ^ 1][i * 512]);
            }
            #pragma unroll
            for (int i = 0; i < 8; ++i) {
                int row = i * 8 + srow, cb = scb ^ (row & 7);
                gl_lds16(Vt + ((i64)b * DH + row) * SEQ + kn + cb * 8, &Vl[buf ^ 1][i * 512]);
            }
            asm volatile("s_waitcnt vmcnt(32)" ::: "memory");
        } else {
            asm volatile("s_waitcnt vmcnt(16)" ::: "memory");
        }

        f32x4 sacc[4] = {};
        #pragma unroll
        for (int tt = 0; tt < 4; ++tt) {
            int row = tt * 16 + lr, x = row & 7;
            short8 k0 = *(const short8*)&Kl[buf][row * 64 + ((lg) ^ x) * 8];
            short8 k1 = *(const short8*)&Kl[buf][row * 64 + ((lg + 4) ^ x) * 8];
            sacc[tt] = MFMA16(qf0, k0, sacc[tt], 0, 0, 0);
            sacc[tt] = MFMA16(qf1, k1, sacc[tt], 0, 0, 0);
        }

        #pragma unroll
        for (int tt = 0; tt < 4; ++tt) {
            #pragma unroll
            for (int r = 0; r < 4; ++r) {
                float p = (mv[tt * 4 + r] != 0) ? __expf(sacc[tt][r] * 0.125f) : 0.0f;
                if      (r == 0) rs0 += p;
                else if (r == 1) rs1 += p;
                else if (r == 2) rs2 += p;
                else             rs3 += p;
                Pl[lg * 4 + r][tt * 16 + lr] = f2bf(p);
            }
        }

        const short8 p0 = *(const short8*)&Pl[lr][lg * 8];
        const short8 p1 = *(const short8*)&Pl[lr][32 + lg * 8];
        #pragma unroll
        for (int vt = 0; vt < 4; ++vt) {
            int row = vt * 16 + lr, x = row & 7;
            short8 v0 = *(const short8*)&Vl[buf][row * 64 + ((lg) ^ x) * 8];
            short8 v1 = *(const short8*)&Vl[buf][row * 64 + ((lg + 4) ^ x) * 8];
            oacc[vt] = MFMA16(p0, v0, oacc[vt], 0, 0, 0);
            oacc[vt] = MFMA16(p1, v1, oacc[vt], 0, 0, 0);
        }
    }

    float rs[4] = {rs0, rs1, rs2, rs3};
    #pragma unroll
    for (int r = 0; r < 4; ++r) {
        float v = rs[r];
        v += __shfl_xor(v, 1, 64);
        v += __shfl_xor(v, 2, 64);
        v += __shfl_xor(v, 4, 64);
        v += __shfl_xor(v, 8, 64);
        rs[r] = 1.0f / v;
    }
    #pragma unroll
    for (int vt = 0; vt < 4; ++vt)
        #pragma unroll
        for (int r = 0; r < 4; ++r)
            out[((i64)b * SEQ + q0 + lg * 4 + r) * DH + vt * 16 + lr] = oacc[vt][r] * rs[r];
}

extern "C" void kernel_launch(void* const* d_in, const int* in_sizes, int n_in,
                              void* d_out, int out_size, void* d_ws, size_t ws_size,
                              hipStream_t stream) {
    const float* kh   = (const float*)d_in[0];
    const float* qh   = (const float*)d_in[1];
    const float* vh   = (const float*)d_in[2];
    const int*   mask = (const int*)  d_in[3];
    const float* Wq   = (const float*)d_in[4];
    const float* bq   = (const float*)d_in[5];
    const float* Wk   = (const float*)d_in[6];
    const float* bk   = (const float*)d_in[7];
    const float* Wv   = (const float*)d_in[8];
    const float* bv   = (const float*)d_in[9];
    float* out = (float*)d_out;

    u16* Wth = (u16*)d_ws;                       // 3*64*1024
    u16* Wtl = Wth + 3 * DH * HIDDEN;            // 3*64*1024
    u16* Qb  = Wtl + 3 * DH * HIDDEN;            // 8*2048*64
    u16* Kb  = Qb + (i64)NB * SEQ * DH;
    u16* Vt  = Kb + (i64)NB * SEQ * DH;          // [b][vd][key]

    wt_prep<<<48, 256, 0, stream>>>(Wq, Wk, Wv, Wth, Wtl);
    proj_mfma6<<<dim3(512, 3), 256, 0, stream>>>(qh, kh, vh, Wth, Wtl,
                                                 bq, bk, bv, Qb, Kb, Vt);
    attn_mfma<<<1024, 64, 0, stream>>>(Qb, Kb, Vt, mask, out);
}

// Round 12
// 120.906 us; speedup vs baseline: 1.7717x; 1.1981x over previous
//
#include <hip/hip_runtime.h>

#define HIDDEN 1024
#define NB 8
#define SEQ 2048
#define DH 64

typedef long long i64;
typedef unsigned short u16;
typedef __attribute__((ext_vector_type(8))) _Float16 half8;  // 4 VGPRs = 8 fp16
typedef __attribute__((ext_vector_type(4))) float f32x4;

#define MFMA16F __builtin_amdgcn_mfma_f32_16x16x32_f16

__device__ __forceinline__ u16 f2h(float x) {
    _Float16 h = (_Float16)x;                 // RNE
    return __builtin_bit_cast(u16, h);
}
__device__ __forceinline__ void gl_lds16(const void* g, void* l) {
    __builtin_amdgcn_global_load_lds(
        (const __attribute__((address_space(1))) unsigned int*)g,
        (__attribute__((address_space(3))) unsigned int*)l, 16, 0, 0);
}

// ---------------------------------------------------------------------------
// Prepass: W[1024][64] (x3) -> Wimg[te][kq][n][bq^(n&7)][j] fp16.
// Transposed + XOR-swizzled image so proj can stage it LINEARLY via
// global_load_lds and read bank-conflict-free (same involution both sides).
// ---------------------------------------------------------------------------
__global__ __launch_bounds__(256) void wimg_prep(
    const float* __restrict__ Wq, const float* __restrict__ Wk, const float* __restrict__ Wv,
    u16* __restrict__ Wimg)
{
    const int t = blockIdx.x * 256 + threadIdx.x;   // 24576 threads
    const int te = t >> 13;                          // 0..2
    const int rem = t & 8191;
    const int n = rem >> 7;                          // 0..63
    const int bb = rem & 127;                        // 16B block over full K
    const int kq = bb >> 5, bq = bb & 31;
    const float* W = te == 0 ? Wq : te == 1 ? Wk : Wv;
    const i64 base = ((i64)(te * 4 + kq) * 64 + n) * 256 + ((bq ^ (n & 7)) << 3);
    #pragma unroll
    for (int j = 0; j < 8; ++j) {
        const int k = kq * 256 + bq * 8 + j;
        Wimg[base + j] = f2h(W[(i64)k * DH + n]);
    }
}

// ---------------------------------------------------------------------------
// Projection v7: fp16 single-pass, W-stationary K-quarter phases.
// Block = 256 thr = 4 waves; block tile = 64 rows x 64 cols, full K=1024.
// Grid (256, 3) = 768 blocks -> 3/CU (LDS 32KB), 12 waves/CU.
// Per phase kq: stage 32KB W-quarter (8 gl_lds/wave, pre-swizzled image,
// linear dest), vmcnt(0)+barrier ONCE, then 8 barrier-free steps (BK=32):
// A read direct from row-major fp32 global (2-step register ring, static
// idx), 1 cvt/elem to fp16, 4 ds_read_b128 (2-way, free) + 4 MFMA.
// ---------------------------------------------------------------------------
__global__ __launch_bounds__(256) void proj_mfma7(
    const float* __restrict__ qh, const float* __restrict__ kh, const float* __restrict__ vh,
    const u16* __restrict__ Wimg,
    const float* __restrict__ bq, const float* __restrict__ bk, const float* __restrict__ bv,
    u16* __restrict__ Qb, u16* __restrict__ Kb, u16* __restrict__ Vt)
{
    const int te = blockIdx.y;
    const float* A    = te == 0 ? qh : te == 1 ? kh : vh;
    const float* bias = te == 0 ? bq : te == 1 ? bk : bv;
    const int row0 = blockIdx.x << 6;
    const int t = threadIdx.x;
    const int w = t >> 6, lane = t & 63;
    const int lr = lane & 15, lg = lane >> 4;

    __shared__ __attribute__((aligned(16))) u16 Wl[16384];   // 32 KB, one K-quarter

    const u16* Wte = Wimg + (i64)te * 4 * 16384;
    const float* arow = A + (i64)(row0 + w * 16 + lr) * HIDDEN + (lg << 3);

    f32x4 acc[4] = {};

    // A register ring, 2 steps deep (ks = global k-step 0..31, BK=32)
    float4 buf0[2], buf1[2];
    buf0[0] = *(const float4*)(arow);
    buf0[1] = *(const float4*)(arow + 4);
    buf1[0] = *(const float4*)(arow + 32);
    buf1[1] = *(const float4*)(arow + 36);

#define CVT8(bf, a8) { \
        const float xs_[8] = {bf[0].x, bf[0].y, bf[0].z, bf[0].w, \
                              bf[1].x, bf[1].y, bf[1].z, bf[1].w}; \
        _Pragma("unroll") \
        for (int j_ = 0; j_ < 8; ++j_) a8[j_] = (_Float16)xs_[j_]; }

    #pragma unroll 1
    for (int kq = 0; kq < 4; ++kq) {
        if (kq) __syncthreads();          // all waves done reading Wl
        // stage K-quarter kq: per wave 8 gl_lds, linear dest (image pre-swizzled)
        {
            const u16* src = Wte + kq * 16384 + (w << 12) + (lane << 3);
            #pragma unroll
            for (int i = 0; i < 8; ++i)
                gl_lds16(src + i * 512, &Wl[(w << 12) + i * 512]);
        }
        asm volatile("s_waitcnt vmcnt(0)" ::: "memory");
        __syncthreads();

        #pragma unroll
        for (int s = 0; s < 8; ++s) {
            const int ks = kq * 8 + s;
            half8 a;
            if ((s & 1) == 0) {
                CVT8(buf0, a)
                const int kn = ((ks + 2) & 31) << 5;     // wrap: harmless re-read
                buf0[0] = *(const float4*)(arow + kn);
                buf0[1] = *(const float4*)(arow + kn + 4);
            } else {
                CVT8(buf1, a)
                const int kn = ((ks + 2) & 31) << 5;
                buf1[0] = *(const float4*)(arow + kn);
                buf1[1] = *(const float4*)(arow + kn + 4);
            }
            const int s4 = s << 2;
            #pragma unroll
            for (int nt = 0; nt < 4; ++nt) {
                const int n = nt * 16 + lr;
                const half8 b = *(const half8*)&Wl[n * 256 + (((s4 + lg) ^ (n & 7)) << 3)];
                acc[nt] = MFMA16F(a, b, acc[nt], 0, 0, 0);
            }
        }
    }
#undef CVT8

    // epilogue: D layout col=lane&15 (within nt), row=(lane>>4)*4+reg
    #pragma unroll
    for (int nt = 0; nt < 4; ++nt) {
        const int col = nt * 16 + lr;
        const float bb = bias[col];
        #pragma unroll
        for (int r = 0; r < 4; ++r) {
            const i64 grow = row0 + w * 16 + (lg << 2) + r;
            const u16 v = f2h(acc[nt][r] + bb);
            if (te == 0)      Qb[grow * DH + col] = v;
            else if (te == 1) Kb[grow * DH + col] = v;
            else {
                const i64 bb2 = grow >> 11, key = grow & 2047;
                Vt[(bb2 * DH + col) * SEQ + key] = v;
            }
        }
    }
}

// ---------------------------------------------------------------------------
// Attention: 1024 single-wave blocks (16 q-rows each), no barriers.
// Same structure as the round-9 passing version; dtype switched to fp16
// (Q/K/V/P fp16, fp32 accumulate). No-max softmax unchanged.
// ---------------------------------------------------------------------------
__global__ __launch_bounds__(64) void attn_mfma(
    const u16* __restrict__ Qb, const u16* __restrict__ Kb, const u16* __restrict__ Vt,
    const int* __restrict__ mask, float* __restrict__ out)
{
    __shared__ __attribute__((aligned(16))) u16 Kl[2][64 * 64];
    __shared__ __attribute__((aligned(16))) u16 Vl[2][64 * 64];
    __shared__ __attribute__((aligned(16))) u16 Pl[16][72];

    const int lane = threadIdx.x;
    const int lr = lane & 15, lg = lane >> 4;
    const int b  = blockIdx.x >> 7;
    const int q0 = (blockIdx.x & 127) << 4;

    const i64 qrow = (i64)b * SEQ + q0 + lr;
    const half8 qf0 = *(const half8*)(Qb + qrow * DH + lg * 8);
    const half8 qf1 = *(const half8*)(Qb + qrow * DH + 32 + lg * 8);

    const int srow = lane >> 3;   // 0..7 (+8i)
    const int scb  = lane & 7;    // 16B block

    f32x4 oacc[4] = {};
    float rs0 = 0.f, rs1 = 0.f, rs2 = 0.f, rs3 = 0.f;

    // prologue: stage tile 0 into buf 0 (16 loads)
    {
        const i64 kbase = (i64)b * SEQ;
        #pragma unroll
        for (int i = 0; i < 8; ++i) {
            int row = i * 8 + srow, cb = scb ^ (row & 7);
            gl_lds16(Kb + (kbase + row) * DH + cb * 8, &Kl[0][i * 512]);
        }
        #pragma unroll
        for (int i = 0; i < 8; ++i) {
            int row = i * 8 + srow, cb = scb ^ (row & 7);
            gl_lds16(Vt + ((i64)b * DH + row) * SEQ + cb * 8, &Vl[0][i * 512]);
        }
    }

    #pragma unroll 1
    for (int t = 0; t < 32; ++t) {
        const int kt = t * 64;
        const int buf = t & 1;

        int mv[16];
        #pragma unroll
        for (int tt = 0; tt < 4; ++tt)
            #pragma unroll
            for (int r = 0; r < 4; ++r)
                mv[tt * 4 + r] =
                    mask[((i64)b * SEQ + q0 + lg * 4 + r) * SEQ + kt + tt * 16 + lr];

        if (t < 31) {
            const int kn = kt + 64;
            const i64 kbase = (i64)b * SEQ + kn;
            #pragma unroll
            for (int i = 0; i < 8; ++i) {
                int row = i * 8 + srow, cb = scb ^ (row & 7);
                gl_lds16(Kb + (kbase + row) * DH + cb * 8, &Kl[buf ^ 1][i * 512]);
            }
            #pragma unroll
            for (int i = 0; i < 8; ++i) {
                int row = i * 8 + srow, cb = scb ^ (row & 7);
                gl_lds16(Vt + ((i64)b * DH + row) * SEQ + kn + cb * 8, &Vl[buf ^ 1][i * 512]);
            }
            asm volatile("s_waitcnt vmcnt(32)" ::: "memory");
        } else {
            asm volatile("s_waitcnt vmcnt(16)" ::: "memory");
        }

        f32x4 sacc[4] = {};
        #pragma unroll
        for (int tt = 0; tt < 4; ++tt) {
            int row = tt * 16 + lr, x = row & 7;
            half8 k0 = *(const half8*)&Kl[buf][row * 64 + ((lg) ^ x) * 8];
            half8 k1 = *(const half8*)&Kl[buf][row * 64 + ((lg + 4) ^ x) * 8];
            sacc[tt] = MFMA16F(qf0, k0, sacc[tt], 0, 0, 0);
            sacc[tt] = MFMA16F(qf1, k1, sacc[tt], 0, 0, 0);
        }

        #pragma unroll
        for (int tt = 0; tt < 4; ++tt) {
            #pragma unroll
            for (int r = 0; r < 4; ++r) {
                float p = (mv[tt * 4 + r] != 0) ? __expf(sacc[tt][r] * 0.125f) : 0.0f;
                if      (r == 0) rs0 += p;
                else if (r == 1) rs1 += p;
                else if (r == 2) rs2 += p;
                else             rs3 += p;
                Pl[lg * 4 + r][tt * 16 + lr] = f2h(p);
            }
        }

        const half8 p0 = *(const half8*)&Pl[lr][lg * 8];
        const half8 p1 = *(const half8*)&Pl[lr][32 + lg * 8];
        #pragma unroll
        for (int vt = 0; vt < 4; ++vt) {
            int row = vt * 16 + lr, x = row & 7;
            half8 v0 = *(const half8*)&Vl[buf][row * 64 + ((lg) ^ x) * 8];
            half8 v1 = *(const half8*)&Vl[buf][row * 64 + ((lg + 4) ^ x) * 8];
            oacc[vt] = MFMA16F(p0, v0, oacc[vt], 0, 0, 0);
            oacc[vt] = MFMA16F(p1, v1, oacc[vt], 0, 0, 0);
        }
    }

    float rs[4] = {rs0, rs1, rs2, rs3};
    #pragma unroll
    for (int r = 0; r < 4; ++r) {
        float v = rs[r];
        v += __shfl_xor(v, 1, 64);
        v += __shfl_xor(v, 2, 64);
        v += __shfl_xor(v, 4, 64);
        v += __shfl_xor(v, 8, 64);
        rs[r] = 1.0f / v;
    }
    #pragma unroll
    for (int vt = 0; vt < 4; ++vt)
        #pragma unroll
        for (int r = 0; r < 4; ++r)
            out[((i64)b * SEQ + q0 + lg * 4 + r) * DH + vt * 16 + lr] = oacc[vt][r] * rs[r];
}

extern "C" void kernel_launch(void* const* d_in, const int* in_sizes, int n_in,
                              void* d_out, int out_size, void* d_ws, size_t ws_size,
                              hipStream_t stream) {
    const float* kh   = (const float*)d_in[0];
    const float* qh   = (const float*)d_in[1];
    const float* vh   = (const float*)d_in[2];
    const int*   mask = (const int*)  d_in[3];
    const float* Wq   = (const float*)d_in[4];
    const float* bq   = (const float*)d_in[5];
    const float* Wk   = (const float*)d_in[6];
    const float* bk   = (const float*)d_in[7];
    const float* Wv   = (const float*)d_in[8];
    const float* bv   = (const float*)d_in[9];
    float* out = (float*)d_out;

    u16* Wimg = (u16*)d_ws;                      // 3*4*16384 u16 = 384 KB
    u16* Qb   = Wimg + 3 * 4 * 16384;            // 8*2048*64 u16 = 2 MB each
    u16* Kb   = Qb + (i64)NB * SEQ * DH;
    u16* Vt   = Kb + (i64)NB * SEQ * DH;         // [b][vd][key]

    wimg_prep<<<96, 256, 0, stream>>>(Wq, Wk, Wv, Wimg);
    proj_mfma7<<<dim3(256, 3), 256, 0, stream>>>(qh, kh, vh, Wimg,
                                                 bq, bk, bv, Qb, Kb, Vt);
    attn_mfma<<<1024, 64, 0, stream>>>(Qb, Kb, Vt, mask, out);
}

// Round 13
// 115.014 us; speedup vs baseline: 1.8624x; 1.0512x over previous
//
#include <hip/hip_runtime.h>

#define HIDDEN 1024
#define NB 8
#define SEQ 2048
#define DH 64

typedef long long i64;
typedef unsigned short u16;
typedef __attribute__((ext_vector_type(8))) _Float16 half8;  // 4 VGPRs = 8 fp16
typedef __attribute__((ext_vector_type(4))) float f32x4;

#define MFMA16F __builtin_amdgcn_mfma_f32_16x16x32_f16

__device__ __forceinline__ u16 f2h(float x) {
    _Float16 h = (_Float16)x;                 // RNE
    return __builtin_bit_cast(u16, h);
}
__device__ __forceinline__ void gl_lds16(const void* g, void* l) {
    __builtin_amdgcn_global_load_lds(
        (const __attribute__((address_space(1))) unsigned int*)g,
        (__attribute__((address_space(3))) unsigned int*)l, 16, 0, 0);
}

// ---------------------------------------------------------------------------
// Prepass: W[1024][64] (x3) -> Wimg[te][p][n][pos] fp16, p = K-phase of 128,
// pos = 16B block; position pos holds global k-chunk (pos ^ (n&7)).
// Image is contiguous in exactly the order proj stages it (pure-linear gl_lds
// source), and the XOR pre-swizzle makes proj's ds_reads conflict-free.
// ---------------------------------------------------------------------------
__global__ __launch_bounds__(256) void wimg_prep8(
    const float* __restrict__ Wq, const float* __restrict__ Wk, const float* __restrict__ Wv,
    u16* __restrict__ Wimg)
{
    const int t = blockIdx.x * 256 + threadIdx.x;   // 24576 threads
    const int te = t >> 13;
    const int rem = t & 8191;
    const int p = rem >> 10;                         // 0..7
    const int rem2 = rem & 1023;
    const int n = rem2 >> 4;                         // 0..63
    const int pos = rem2 & 15;                       // 16B block in phase
    const float* W = te == 0 ? Wq : te == 1 ? Wk : Wv;
    const int g = pos ^ (n & 7);
    const int k0 = p * 128 + g * 8;
    u16* dst = Wimg + (i64)t * 8;
    #pragma unroll
    for (int j = 0; j < 8; ++j)
        dst[j] = f2h(W[(i64)(k0 + j) * DH + n]);
}

// ---------------------------------------------------------------------------
// Projection v8: contiguous-stream staging (the attn-proven memory pipeline).
// Block = 256 thr = 4 waves, tile 32 rows x 64 cols, K phased by BK=128.
// Per phase: A-slab 32x128 fp32 (16KB) staged via gl_lds with >=512B
// contiguous source chunks + XOR-pre-swizzled source; W-tile 64x128 fp16
// (16KB) staged linearly from the pre-swizzled image. Double-buffered;
// order per phase: vmcnt(0)[own stage only] -> barrier -> stage(p+1) ->
// compute(p). Waves: w -> rows (w&1)*16, cols (w>>1)*32.
// ---------------------------------------------------------------------------
__global__ __launch_bounds__(256) void proj_mfma8(
    const float* __restrict__ qh, const float* __restrict__ kh, const float* __restrict__ vh,
    const u16* __restrict__ Wimg,
    const float* __restrict__ bq, const float* __restrict__ bk, const float* __restrict__ bv,
    u16* __restrict__ Qb, u16* __restrict__ Kb, u16* __restrict__ Vt)
{
    const int te = blockIdx.y;
    const float* A    = te == 0 ? qh : te == 1 ? kh : vh;
    const float* bias = te == 0 ? bq : te == 1 ? bk : bv;
    const int row0 = blockIdx.x << 5;          // 512 row-blocks of 32
    const int t = threadIdx.x;
    const int w = t >> 6, lane = t & 63;
    const int lr = lane & 15, lg = lane >> 4;
    const int wr = (w & 1) << 4;               // wave row offset
    const int wc = (w >> 1) << 5;              // wave col offset

    __shared__ __attribute__((aligned(16))) float AL[2][32 * 128];  // 16KB x2
    __shared__ __attribute__((aligned(16))) u16  WL[2][64 * 128];   // 16KB x2

    const u16* Wte = Wimg + (i64)te * 8 * 8192;

    // staging addresses (per wave: 4 A gl_lds + 4 W gl_lds per phase)
    const float* asrc[4]; int adst[4];
    #pragma unroll
    for (int i = 0; i < 4; ++i) {
        const int r0 = 8 * w + 2 * i;              // 2 rows per gl_lds
        const int rl = r0 + (lane >> 5);           // this lane's row
        asrc[i] = A + (i64)(row0 + rl) * HIDDEN + (((lane & 31) ^ (rl & 7)) << 2);
        adst[i] = r0 * 128;
    }
    const u16* wsrc[4]; int wdst[4];
    #pragma unroll
    for (int i = 0; i < 4; ++i) {
        const int n0 = 16 * w + 4 * i;             // 4 W-rows per gl_lds
        wsrc[i] = Wte + n0 * 128 + (lane << 3);    // contiguous 1KB
        wdst[i] = n0 * 128;
    }

    f32x4 acc[2] = {};

#define STAGE8(bufi, p) { \
        _Pragma("unroll") \
        for (int i_ = 0; i_ < 4; ++i_) \
            gl_lds16(asrc[i_] + (p) * 128, &AL[bufi][adst[i_]]); \
        _Pragma("unroll") \
        for (int i_ = 0; i_ < 4; ++i_) \
            gl_lds16(wsrc[i_] + (p) * 8192, &WL[bufi][wdst[i_]]); }

    STAGE8(0, 0)

    int buf = 0;
    #pragma unroll 1
    for (int p = 0; p < 8; ++p) {
        asm volatile("s_waitcnt vmcnt(0)" ::: "memory");   // only own stage(p) outstanding
        __syncthreads();                                    // stage(p) visible; buf^1 free
        if (p < 7) STAGE8(buf ^ 1, p + 1)
        const int x = lr & 7;
        #pragma unroll
        for (int ks = 0; ks < 4; ++ks) {
            const int b0 = ks * 8 + lg * 2;
            const float4 fa = *(const float4*)&AL[buf][(wr + lr) * 128 + ((b0 ^ x) << 2)];
            const float4 fb = *(const float4*)&AL[buf][(wr + lr) * 128 + (((b0 + 1) ^ x) << 2)];
            half8 a;
            a[0] = (_Float16)fa.x; a[1] = (_Float16)fa.y;
            a[2] = (_Float16)fa.z; a[3] = (_Float16)fa.w;
            a[4] = (_Float16)fb.x; a[5] = (_Float16)fb.y;
            a[6] = (_Float16)fb.z; a[7] = (_Float16)fb.w;
            #pragma unroll
            for (int nt = 0; nt < 2; ++nt) {
                const int n = wc + nt * 16 + lr;           // n&7 == lr&7 == x
                const int pos = (ks * 4 + lg) ^ x;
                const half8 bfr = *(const half8*)&WL[buf][n * 128 + (pos << 3)];
                acc[nt] = MFMA16F(a, bfr, acc[nt], 0, 0, 0);
            }
        }
        buf ^= 1;
    }
#undef STAGE8

    // epilogue: D layout col=lane&15 (within nt), row=(lane>>4)*4+reg
    #pragma unroll
    for (int nt = 0; nt < 2; ++nt) {
        const int col = wc + nt * 16 + lr;
        const float bb = bias[col];
        #pragma unroll
        for (int r = 0; r < 4; ++r) {
            const i64 grow = row0 + wr + (lg << 2) + r;
            const u16 v = f2h(acc[nt][r] + bb);
            if (te == 0)      Qb[grow * DH + col] = v;
            else if (te == 1) Kb[grow * DH + col] = v;
            else {
                const i64 bb2 = grow >> 11, key = grow & 2047;
                Vt[(bb2 * DH + col) * SEQ + key] = v;
            }
        }
    }
}

// ---------------------------------------------------------------------------
// Attention: 1024 single-wave blocks (16 q-rows each), no barriers.
// (byte-identical to the round-12 passing fp16 version)
// ---------------------------------------------------------------------------
__global__ __launch_bounds__(64) void attn_mfma(
    const u16* __restrict__ Qb, const u16* __restrict__ Kb, const u16* __restrict__ Vt,
    const int* __restrict__ mask, float* __restrict__ out)
{
    __shared__ __attribute__((aligned(16))) u16 Kl[2][64 * 64];
    __shared__ __attribute__((aligned(16))) u16 Vl[2][64 * 64];
    __shared__ __attribute__((aligned(16))) u16 Pl[16][72];

    const int lane = threadIdx.x;
    const int lr = lane & 15, lg = lane >> 4;
    const int b  = blockIdx.x >> 7;
    const int q0 = (blockIdx.x & 127) << 4;

    const i64 qrow = (i64)b * SEQ + q0 + lr;
    const half8 qf0 = *(const half8*)(Qb + qrow * DH + lg * 8);
    const half8 qf1 = *(const half8*)(Qb + qrow * DH + 32 + lg * 8);

    const int srow = lane >> 3;   // 0..7 (+8i)
    const int scb  = lane & 7;    // 16B block

    f32x4 oacc[4] = {};
    float rs0 = 0.f, rs1 = 0.f, rs2 = 0.f, rs3 = 0.f;

    // prologue: stage tile 0 into buf 0 (16 loads)
    {
        const i64 kbase = (i64)b * SEQ;
        #pragma unroll
        for (int i = 0; i < 8; ++i) {
            int row = i * 8 + srow, cb = scb ^ (row & 7);
            gl_lds16(Kb + (kbase + row) * DH + cb * 8, &Kl[0][i * 512]);
        }
        #pragma unroll
        for (int i = 0; i < 8; ++i) {
            int row = i * 8 + srow, cb = scb ^ (row & 7);
            gl_lds16(Vt + ((i64)b * DH + row) * SEQ + cb * 8, &Vl[0][i * 512]);
        }
    }

    #pragma unroll 1
    for (int t = 0; t < 32; ++t) {
        const int kt = t * 64;
        const int buf = t & 1;

        int mv[16];
        #pragma unroll
        for (int tt = 0; tt < 4; ++tt)
            #pragma unroll
            for (int r = 0; r < 4; ++r)
                mv[tt * 4 + r] =
                    mask[((i64)b * SEQ + q0 + lg * 4 + r) * SEQ + kt + tt * 16 + lr];

        if (t < 31) {
            const int kn = kt + 64;
            const i64 kbase = (i64)b * SEQ + kn;
            #pragma unroll
            for (int i = 0; i < 8; ++i) {
                int row = i * 8 + srow, cb = scb ^ (row & 7);
                gl_lds16(Kb + (kbase + row) * DH + cb * 8, &Kl[buf ^ 1][i * 512]);
            }
            #pragma unroll
            for (int i = 0; i < 8; ++i) {
                int row = i * 8 + srow, cb = scb ^ (row & 7);
                gl_lds16(Vt + ((i64)b * DH + row) * SEQ + kn + cb * 8, &Vl[buf ^ 1][i * 512]);
            }
            asm volatile("s_waitcnt vmcnt(32)" ::: "memory");
        } else {
            asm volatile("s_waitcnt vmcnt(16)" ::: "memory");
        }

        f32x4 sacc[4] = {};
        #pragma unroll
        for (int tt = 0; tt < 4; ++tt) {
            int row = tt * 16 + lr, x = row & 7;
            half8 k0 = *(const half8*)&Kl[buf][row * 64 + ((lg) ^ x) * 8];
            half8 k1 = *(const half8*)&Kl[buf][row * 64 + ((lg + 4) ^ x) * 8];
            sacc[tt] = MFMA16F(qf0, k0, sacc[tt], 0, 0, 0);
            sacc[tt] = MFMA16F(qf1, k1, sacc[tt], 0, 0, 0);
        }

        #pragma unroll
        for (int tt = 0; tt < 4; ++tt) {
            #pragma unroll
            for (int r = 0; r < 4; ++r) {
                float p = (mv[tt * 4 + r] != 0) ? __expf(sacc[tt][r] * 0.125f) : 0.0f;
                if      (r == 0) rs0 += p;
                else if (r == 1) rs1 += p;
                else if (r == 2) rs2 += p;
                else             rs3 += p;
                Pl[lg * 4 + r][tt * 16 + lr] = f2h(p);
            }
        }

        const half8 p0 = *(const half8*)&Pl[lr][lg * 8];
        const half8 p1 = *(const half8*)&Pl[lr][32 + lg * 8];
        #pragma unroll
        for (int vt = 0; vt < 4; ++vt) {
            int row = vt * 16 + lr, x = row & 7;
            half8 v0 = *(const half8*)&Vl[buf][row * 64 + ((lg) ^ x) * 8];
            half8 v1 = *(const half8*)&Vl[buf][row * 64 + ((lg + 4) ^ x) * 8];
            oacc[vt] = MFMA16F(p0, v0, oacc[vt], 0, 0, 0);
            oacc[vt] = MFMA16F(p1, v1, oacc[vt], 0, 0, 0);
        }
    }

    float rs[4] = {rs0, rs1, rs2, rs3};
    #pragma unroll
    for (int r = 0; r < 4; ++r) {
        float v = rs[r];
        v += __shfl_xor(v, 1, 64);
        v += __shfl_xor(v, 2, 64);
        v += __shfl_xor(v, 4, 64);
        v += __shfl_xor(v, 8, 64);
        rs[r] = 1.0f / v;
    }
    #pragma unroll
    for (int vt = 0; vt < 4; ++vt)
        #pragma unroll
        for (int r = 0; r < 4; ++r)
            out[((i64)b * SEQ + q0 + lg * 4 + r) * DH + vt * 16 + lr] = oacc[vt][r] * rs[r];
}

extern "C" void kernel_launch(void* const* d_in, const int* in_sizes, int n_in,
                              void* d_out, int out_size, void* d_ws, size_t ws_size,
                              hipStream_t stream) {
    const float* kh   = (const float*)d_in[0];
    const float* qh   = (const float*)d_in[1];
    const float* vh   = (const float*)d_in[2];
    const int*   mask = (const int*)  d_in[3];
    const float* Wq   = (const float*)d_in[4];
    const float* bq   = (const float*)d_in[5];
    const float* Wk   = (const float*)d_in[6];
    const float* bk   = (const float*)d_in[7];
    const float* Wv   = (const float*)d_in[8];
    const float* bv   = (const float*)d_in[9];
    float* out = (float*)d_out;

    u16* Wimg = (u16*)d_ws;                      // 3*8*8192 u16 = 384 KB
    u16* Qb   = Wimg + 3 * 8 * 8192;             // 2 MB each
    u16* Kb   = Qb + (i64)NB * SEQ * DH;
    u16* Vt   = Kb + (i64)NB * SEQ * DH;         // [b][vd][key]

    wimg_prep8<<<96, 256, 0, stream>>>(Wq, Wk, Wv, Wimg);
    proj_mfma8<<<dim3(512, 3), 256, 0, stream>>>(qh, kh, vh, Wimg,
                                                 bq, bk, bv, Qb, Kb, Vt);
    attn_mfma<<<1024, 64, 0, stream>>>(Qb, Kb, Vt, mask, out);
}